// Round 4
// baseline (165.784 us; speedup 1.0000x reference)
//
#include <hip/hip_runtime.h>

#define POOL 7
#define NCH 256
#define OUT_PER_BOX (NCH * POOL * POOL)   // 12544
#define NSLICE 28
#define SLICE_SZ (OUT_PER_BOX / NSLICE)   // 448 outputs (~10 channels) per slice
#define G 8                                // boxes per group (sorted, overlapping)
#define NBINS 64
#define PWORDS 64                          // int words per box in params buffer

// params layout per sorted box (ints; floats bit-cast):
//  [0..6]   y0*H (row offset)   [7..13]  y1*H
//  [14..20] xb (pair base col)  [21..27] xcl flag
//  [28..34] wy bits             [35..41] wx bits
//  [42..48] vy bits             [49..55] vx bits
//  [56] lvl-2   [57] H   [58] H*H   [59] original box id

__device__ __forceinline__ void box_params(
    const float* __restrict__ boxes, int i, int* __restrict__ P, int* lvl_out)
{
    const float by1 = boxes[i * 4 + 0];
    const float bx1 = boxes[i * 4 + 1];
    const float by2 = boxes[i * 4 + 2];
    const float bx2 = boxes[i * 4 + 3];
    const float h = by2 - by1;
    const float w = bx2 - bx1;
    const float lvlf = 4.0f + log2f(sqrtf(h * w) / 0.21875f);
    int lvl = (int)rintf(lvlf);               // round-half-even = jnp.round
    lvl = lvl < 2 ? 2 : (lvl > 5 ? 5 : lvl);
    const int H = 256 >> (lvl - 2);
    const float Hm1 = (float)(H - 1);

    #pragma unroll
    for (int t = 0; t < POOL; ++t) {
        const float tt = (float)t * (1.0f / 6.0f);

        const float yy  = (by1 + h * tt) * Hm1;
        const float y0f = floorf(yy);
        int y0 = (int)y0f;
        y0 = min(H - 1, max(0, y0));
        P[t]      = y0 * H;
        P[7 + t]  = min(H - 1, y0 + 1) * H;
        P[28 + t] = __float_as_int(yy - y0f);                 // weight from UNCLIPPED floor
        P[42 + t] = __float_as_int((yy >= 0.0f && yy <= Hm1) ? 1.0f : 0.0f);

        const float xx  = (bx1 + w * tt) * Hm1;
        const float x0f = floorf(xx);
        int x0 = (int)x0f;
        x0 = min(H - 1, max(0, x0));
        P[14 + t] = min(x0, H - 2);                            // float2 pair base
        P[21 + t] = (x0 == H - 1) ? 1 : 0;                     // clamp flag
        P[35 + t] = __float_as_int(xx - x0f);
        P[49 + t] = __float_as_int((xx >= 0.0f && xx <= Hm1) ? 1.0f : 0.0f);
    }
    P[56] = lvl - 2;
    P[57] = H;
    P[58] = H * H;
    P[59] = i;
    *lvl_out = lvl;
}

// ---------------------------------------------------------------------------
// Prepass: counting-sort boxes into (level, 4x4 quadrant) bins and write the
// per-box sampling params in SORTED order. Order within a bin is arbitrary.
// ---------------------------------------------------------------------------
__global__ __launch_bounds__(1024) void prep_kernel(
    const float* __restrict__ boxes, int* __restrict__ params, int nbox)
{
    __shared__ int s_cnt[NBINS], s_off[NBINS];
    const int i = threadIdx.x;
    if (i < NBINS) s_cnt[i] = 0;
    __syncthreads();

    int bin = -1;
    if (i < nbox) {
        const float y1 = boxes[i * 4 + 0];
        const float x1 = boxes[i * 4 + 1];
        const float y2 = boxes[i * 4 + 2];
        const float x2 = boxes[i * 4 + 3];
        const float h = y2 - y1;
        const float w = x2 - x1;
        const float lvlf = 4.0f + log2f(sqrtf(h * w) * (1.0f / 0.21875f));
        int lvl = (int)rintf(lvlf);
        lvl = lvl < 2 ? 2 : (lvl > 5 ? 5 : lvl);
        const float cy = 0.5f * (y1 + y2);
        const float cx = 0.5f * (x1 + x2);
        int qy = (int)(cy * 4.0f); qy = qy < 0 ? 0 : (qy > 3 ? 3 : qy);
        int qx = (int)(cx * 4.0f); qx = qx < 0 ? 0 : (qx > 3 ? 3 : qx);
        bin = ((lvl - 2) << 4) | (qy << 2) | qx;
        atomicAdd(&s_cnt[bin], 1);
    }
    __syncthreads();
    if (i == 0) {
        int acc = 0;
        for (int b = 0; b < NBINS; ++b) { s_off[b] = acc; acc += s_cnt[b]; }
    }
    __syncthreads();
    if (i < nbox) {
        const int pos = atomicAdd(&s_off[bin], 1);
        int dummy;
        box_params(boxes, i, params + pos * PWORDS, &dummy);
    }
}

// Fallback for nbox > 1024: unsorted params (identity order).
__global__ void prep_flat_kernel(
    const float* __restrict__ boxes, int* __restrict__ params, int nbox)
{
    const int i = blockIdx.x * blockDim.x + threadIdx.x;
    if (i >= nbox) return;
    int dummy;
    box_params(boxes, i, params + i * PWORDS, &dummy);
}

// ---------------------------------------------------------------------------
// Main kernel: block = (slice s of 28, group g of G sorted boxes).
// Walks its G overlapping boxes sequentially for a ~10-channel slice, so box
// k+1's gather lines hit L1 (32 KiB >> 10ch x ~25 lines). 2-deep software
// pipeline keeps 8 loads in flight.
// ---------------------------------------------------------------------------
#define ISSUE(kk, Q00, Q01, Q10, Q11) do {                                   \
    const int* P = sp[(kk)];                                                 \
    const int lv = __builtin_amdgcn_readfirstlane(P[56]);                    \
    const int HW = __builtin_amdgcn_readfirstlane(P[58]);                    \
    const float* fm = lv == 0 ? p2 : lv == 1 ? p3 : lv == 2 ? p4 : p5;       \
    { const int a = c0 * HW + P[14 + px0];                                   \
      Q00 = *(const float2*)(fm + a + P[py0]);                               \
      Q01 = *(const float2*)(fm + a + P[7 + py0]); }                         \
    if (has1) {                                                              \
      const int a = c1 * HW + P[14 + px1];                                   \
      Q10 = *(const float2*)(fm + a + P[py1]);                               \
      Q11 = *(const float2*)(fm + a + P[7 + py1]); }                         \
} while (0)

#define FINISH(kk, Q00, Q01, Q10, Q11) do {                                  \
    const int* P = sp[(kk)];                                                 \
    const int n = __builtin_amdgcn_readfirstlane(P[59]);                     \
    const size_t ob = (size_t)n * OUT_PER_BOX + s * SLICE_SZ + tid;          \
    {                                                                        \
        const float wy = __int_as_float(P[28 + py0]);                        \
        const float wx = __int_as_float(P[35 + px0]);                        \
        const float vv = __int_as_float(P[42 + py0]) *                       \
                         __int_as_float(P[49 + px0]);                        \
        const int   cl = P[21 + px0];                                        \
        const float v00 = cl ? Q00.y : Q00.x;                                \
        const float v01 = Q00.y;                                             \
        const float v10 = cl ? Q01.y : Q01.x;                                \
        const float v11 = Q01.y;                                             \
        const float r0v = v00 + wx * (v01 - v00);                            \
        const float r1v = v10 + wx * (v11 - v10);                            \
        out[ob] = (r0v + wy * (r1v - r0v)) * vv;                             \
    }                                                                        \
    if (has1) {                                                              \
        const float wy = __int_as_float(P[28 + py1]);                        \
        const float wx = __int_as_float(P[35 + px1]);                        \
        const float vv = __int_as_float(P[42 + py1]) *                       \
                         __int_as_float(P[49 + px1]);                        \
        const int   cl = P[21 + px1];                                        \
        const float v00 = cl ? Q10.y : Q10.x;                                \
        const float v01 = Q10.y;                                             \
        const float v10 = cl ? Q11.y : Q11.x;                                \
        const float v11 = Q11.y;                                             \
        const float r0v = v00 + wx * (v01 - v00);                            \
        const float r1v = v10 + wx * (v11 - v10);                            \
        out[ob + 256] = (r0v + wy * (r1v - r0v)) * vv;                       \
    }                                                                        \
} while (0)

__global__ __launch_bounds__(256) void roi_align_kernel(
    const float* __restrict__ p2,
    const float* __restrict__ p3,
    const float* __restrict__ p4,
    const float* __restrict__ p5,
    float* __restrict__ out,
    const int* __restrict__ params,
    int nbox)
{
    const int s   = blockIdx.x % NSLICE;
    const int g   = blockIdx.x / NSLICE;
    const int tid = threadIdx.x;
    const int base = g * G;
    const int cnt  = min(G, nbox - base);

    __shared__ int sp[G][PWORDS];
    {
        const int total = cnt * PWORDS;
        for (int j = tid; j < G * PWORDS; j += 256)
            sp[0][j] = (j < total) ? params[base * PWORDS + j] : 0;
    }
    __syncthreads();

    // per-thread output coordinates (constant across the box loop)
    const int idx0 = s * SLICE_SZ + tid;
    const int c0  = idx0 / 49;
    const int r0  = idx0 - c0 * 49;
    const int py0 = r0 / 7;
    const int px0 = r0 - py0 * 7;
    const bool has1 = (tid < SLICE_SZ - 256);   // 192 = 3 full waves
    const int idx1 = idx0 + 256;
    const int c1  = idx1 / 49;
    const int r1  = idx1 - c1 * 49;
    const int py1 = r1 / 7;
    const int px1 = r1 - py1 * 7;

    float2 A00 = {0,0}, A01 = {0,0}, A10 = {0,0}, A11 = {0,0};
    float2 B00 = {0,0}, B01 = {0,0}, B10 = {0,0}, B11 = {0,0};

    ISSUE(0, A00, A01, A10, A11);
    #pragma unroll
    for (int k = 0; k < G; k += 2) {
        if (k >= cnt) break;
        if (k + 1 < cnt) ISSUE(k + 1, B00, B01, B10, B11);
        FINISH(k, A00, A01, A10, A11);
        if (k + 1 >= cnt) break;
        if (k + 2 < cnt) ISSUE(k + 2, A00, A01, A10, A11);
        FINISH(k + 1, B00, B01, B10, B11);
    }
}

// ---------------------------------------------------------------------------
// Safety fallback (workspace too small): the verified round-0 flat kernel.
// ---------------------------------------------------------------------------
#define PARTS 7
#define PART_SZ (OUT_PER_BOX / PARTS)
#define ITERS (PART_SZ / 256)

__global__ __launch_bounds__(256) void roi_align_flat_kernel(
    const float* __restrict__ boxes,
    const float* __restrict__ p2, const float* __restrict__ p3,
    const float* __restrict__ p4, const float* __restrict__ p5,
    float* __restrict__ out, int nbox)
{
    const int n    = blockIdx.x % nbox;
    const int part = blockIdx.x / nbox;
    const int tid  = threadIdx.x;

    __shared__ int   s_y0[POOL], s_y1[POOL], s_xb[POOL], s_xcl[POOL];
    __shared__ float s_wy[POOL], s_wx[POOL], s_vy[POOL], s_vx[POOL];

    const float by1 = boxes[n * 4 + 0];
    const float bx1 = boxes[n * 4 + 1];
    const float by2 = boxes[n * 4 + 2];
    const float bx2 = boxes[n * 4 + 3];
    const float h = by2 - by1;
    const float w = bx2 - bx1;
    const float lvlf = 4.0f + log2f(sqrtf(h * w) / 0.21875f);
    int lvl = (int)rintf(lvlf);
    lvl = lvl < 2 ? 2 : (lvl > 5 ? 5 : lvl);

    const float* fm;
    int H;
    switch (lvl) {
        case 2:  fm = p2; H = 256; break;
        case 3:  fm = p3; H = 128; break;
        case 4:  fm = p4; H = 64;  break;
        default: fm = p5; H = 32;  break;
    }
    const float Hm1 = (float)(H - 1);

    if (tid < POOL) {
        const float t = (float)tid * (1.0f / 6.0f);
        const float yy  = (by1 + h * t) * Hm1;
        const float y0f = floorf(yy);
        int y0 = (int)y0f;
        y0 = min(H - 1, max(0, y0));
        s_y0[tid] = y0;
        s_y1[tid] = min(H - 1, y0 + 1);
        s_wy[tid] = yy - y0f;
        s_vy[tid] = (yy >= 0.0f && yy <= Hm1) ? 1.0f : 0.0f;
        const float xx  = (bx1 + w * t) * Hm1;
        const float x0f = floorf(xx);
        int x0 = (int)x0f;
        x0 = min(H - 1, max(0, x0));
        s_xb[tid]  = min(x0, H - 2);
        s_xcl[tid] = (x0 == H - 1) ? 1 : 0;
        s_wx[tid]  = xx - x0f;
        s_vx[tid]  = (xx >= 0.0f && xx <= Hm1) ? 1.0f : 0.0f;
    }
    __syncthreads();

    const size_t out_base = (size_t)n * OUT_PER_BOX + (size_t)part * PART_SZ;
    const int idx0 = part * PART_SZ + tid;
    const int HW = H * H;

    float2 q0[ITERS], q1[ITERS];
    #pragma unroll
    for (int i = 0; i < ITERS; ++i) {
        const int idx = idx0 + i * 256;
        const int c  = idx / 49;
        const int r  = idx - c * 49;
        const int py = r / 7;
        const int px = r - py * 7;
        const float* fmc = fm + (size_t)c * HW;
        const int xb = s_xb[px];
        q0[i] = *(const float2*)(fmc + s_y0[py] * H + xb);
        q1[i] = *(const float2*)(fmc + s_y1[py] * H + xb);
    }
    #pragma unroll
    for (int i = 0; i < ITERS; ++i) {
        const int idx = idx0 + i * 256;
        const int c  = idx / 49;
        const int r  = idx - c * 49;
        const int py = r / 7;
        const int px = r - py * 7;
        const float wy = s_wy[py], wx = s_wx[px];
        const int   cl = s_xcl[px];
        const float v00 = cl ? q0[i].y : q0[i].x;
        const float v01 = q0[i].y;
        const float v10 = cl ? q1[i].y : q1[i].x;
        const float v11 = q1[i].y;
        const float r0 = v00 + wx * (v01 - v00);
        const float r1 = v10 + wx * (v11 - v10);
        out[out_base + (size_t)(i * 256 + tid)] = (r0 + wy * (r1 - r0)) * s_vy[py] * s_vx[px];
    }
}

extern "C" void kernel_launch(void* const* d_in, const int* in_sizes, int n_in,
                              void* d_out, int out_size, void* d_ws, size_t ws_size,
                              hipStream_t stream) {
    const float* boxes = (const float*)d_in[0];
    const float* p2    = (const float*)d_in[1];
    const float* p3    = (const float*)d_in[2];
    const float* p4    = (const float*)d_in[3];
    const float* p5    = (const float*)d_in[4];
    float* out         = (float*)d_out;

    const int nbox = in_sizes[0] / 4;   // 1000
    const size_t need = (size_t)nbox * PWORDS * sizeof(int);   // 256 KB @ 1000

    if (ws_size < need) {
        // workspace too small: verified flat kernel
        roi_align_flat_kernel<<<nbox * PARTS, 256, 0, stream>>>(
            boxes, p2, p3, p4, p5, out, nbox);
        return;
    }

    int* params = (int*)d_ws;
    if (nbox <= 1024) {
        prep_kernel<<<1, 1024, 0, stream>>>(boxes, params, nbox);
    } else {
        prep_flat_kernel<<<(nbox + 255) / 256, 256, 0, stream>>>(boxes, params, nbox);
    }

    const int ngroups = (nbox + G - 1) / G;   // 125
    roi_align_kernel<<<ngroups * NSLICE, 256, 0, stream>>>(
        p2, p3, p4, p5, out, params, nbox);
}